// Round 4
// baseline (175.177 us; speedup 1.0000x reference)
//
#include <hip/hip_runtime.h>
#include <hip/hip_bf16.h>

// fast sigmoid / tanh via native v_exp_f32 + v_rcp_f32 (~1e-6 rel err, fine vs 2%-of-max threshold)
__device__ __forceinline__ float sigf(float x) {
  return __builtin_amdgcn_rcpf(1.0f + __expf(-x));
}
__device__ __forceinline__ float tanh_fast(float x) {
  // tanh(x) = 1 - 2/(1+e^{2x}); saturates cleanly for |x| large
  return fmaf(-2.0f, __builtin_amdgcn_rcpf(1.0f + __expf(2.0f * x)), 1.0f);
}

// B=16384, T=64, H=8. 8 lanes per batch element (lane j = hidden unit j).
// Block = 256 threads = 32 elements; grid = 512 blocks = 2 blocks/CU.
__launch_bounds__(256, 2)
__global__ void lstm_fused(
    const int* __restrict__ x,
    const float* __restrict__ e1, const float* __restrict__ e2,
    const float* __restrict__ e3, const float* __restrict__ e4,
    const float* __restrict__ e5, const float* __restrict__ e6,
    const float* __restrict__ e7, const float* __restrict__ e8,
    const float* __restrict__ W_ih0, const float* __restrict__ W_hh0,
    const float* __restrict__ b_ih0, const float* __restrict__ b_hh0,
    const float* __restrict__ W_ih1, const float* __restrict__ W_hh1,
    const float* __restrict__ b_ih1, const float* __restrict__ b_hh1,
    const float* __restrict__ fc6_w, const float* __restrict__ fc6_b,
    const float* __restrict__ fc7_w, const float* __restrict__ fc7_b,
    const float* __restrict__ fc1_w, const float* __restrict__ fc1_b,
    const float* __restrict__ fc2_w, const float* __restrict__ fc2_b,
    const float* __restrict__ fc3_w, const float* __restrict__ fc3_b,
    float* __restrict__ out)
{
  // Fused embedding×W_ih0 tables: 100 rows × 32 gate-values, stored per-unit
  // permuted: sTf[row*32 + j*4 + q]  (q: 0=i,1=f,2=g,3=o for unit j)
  __shared__ __align__(16) float sTf[3200];
  __shared__ float sW3[64];
  __shared__ __align__(16) float sH0[256];
  __shared__ __align__(16) float sH1[256];

  const int tid = threadIdx.x;

  // ---- build fused input tables in LDS (one-time, ~13 iters/thread) ----
  {
    constexpr int RO[8]  = {0,2,4,25,47,52,54,76};   // cumulative vocab row offsets
    constexpr int ED[8]  = {1,1,3,3,1,1,3,3};        // embedding dims
    constexpr int CO[8]  = {0,1,2,5,8,9,10,13};      // column offsets into 16-dim input
    constexpr int VOC[8] = {2,2,21,22,5,2,22,24};
    const float* ep[8] = {e1,e2,e3,e4,e5,e6,e7,e8};
    #pragma unroll
    for (int f = 0; f < 8; ++f) {
      const float* E = ep[f];
      for (int idx = tid; idx < VOC[f]*32; idx += 256) {
        int v = idx >> 5, m = idx & 31;
        int jj = m >> 2, q = m & 3, g = q*8 + jj;
        float s = 0.0f;
        #pragma unroll
        for (int d = 0; d < ED[f]; ++d)
          s += E[v*ED[f]+d] * W_ih0[g*16 + CO[f] + d];
        if (f == 0) s += b_ih0[g] + b_hh0[g];  // fold both biases into feat-0 table
        sTf[(RO[f]+v)*32 + m] = s;
      }
    }
    if (tid < 64) sW3[tid] = fc3_w[tid];
  }
  __syncthreads();

  const int j = tid & 7;                         // hidden unit owned by this lane
  const int b = (blockIdx.x << 5) + (tid >> 3);  // batch element

  // ---- per-lane recurrent weights in VGPRs (rows q*8+j of each 32x8 matrix) ----
  float wr0[32], wi1[32], wr1[32];
  {
    const float4* p0 = (const float4*)W_hh0;   // [32][8] f32 = 2 float4 per row
    const float4* p1 = (const float4*)W_ih1;
    const float4* p2 = (const float4*)W_hh1;
    #pragma unroll
    for (int q = 0; q < 4; ++q) {
      int r = (q*8 + j) * 2;
      float4 a0 = p0[r], a1 = p0[r+1];
      float4 c0_ = p1[r], c1_ = p1[r+1];
      float4 d0 = p2[r], d1 = p2[r+1];
      wr0[q*8+0]=a0.x; wr0[q*8+1]=a0.y; wr0[q*8+2]=a0.z; wr0[q*8+3]=a0.w;
      wr0[q*8+4]=a1.x; wr0[q*8+5]=a1.y; wr0[q*8+6]=a1.z; wr0[q*8+7]=a1.w;
      wi1[q*8+0]=c0_.x; wi1[q*8+1]=c0_.y; wi1[q*8+2]=c0_.z; wi1[q*8+3]=c0_.w;
      wi1[q*8+4]=c1_.x; wi1[q*8+5]=c1_.y; wi1[q*8+6]=c1_.z; wi1[q*8+7]=c1_.w;
      wr1[q*8+0]=d0.x; wr1[q*8+1]=d0.y; wr1[q*8+2]=d0.z; wr1[q*8+3]=d0.w;
      wr1[q*8+4]=d1.x; wr1[q*8+5]=d1.y; wr1[q*8+6]=d1.z; wr1[q*8+7]=d1.w;
    }
  }
  float4 b1v;  // layer-1 combined bias for unit j, gates i,f,g,o
  b1v.x = b_ih1[j]    + b_hh1[j];
  b1v.y = b_ih1[8+j]  + b_hh1[8+j];
  b1v.z = b_ih1[16+j] + b_hh1[16+j];
  b1v.w = b_ih1[24+j] + b_hh1[24+j];

  // ---- collapsed FC heads: theta = out.u + cth ; hfc = out.v + chh ----
  float uu[8], vv[8], f7[4], f2c[4];
  #pragma unroll
  for (int q = 0; q < 4; ++q) { f7[q] = fc7_w[q]; f2c[q] = fc2_w[q]; }
  #pragma unroll
  for (int k = 0; k < 8; ++k) {
    float s1 = 0.f, s2 = 0.f;
    #pragma unroll
    for (int q = 0; q < 4; ++q) {
      s1 += f7[q]  * fc6_w[q*8+k];
      s2 += f2c[q] * fc1_w[q*8+k];
    }
    uu[k] = s1; vv[k] = s2;
  }
  float cth = fc7_b[0], chh = fc2_b[0];
  #pragma unroll
  for (int q = 0; q < 4; ++q) { cth += f7[q]*fc6_b[q]; chh += f2c[q]*fc1_b[q]; }
  const float fc3b = fc3_b[0];

  // ---- state ----
  float h0v[8], h1v[8];
  #pragma unroll
  for (int k = 0; k < 8; ++k) { h0v[k] = 0.f; h1v[k] = 0.f; }
  float c0 = 0.f, c1 = 0.f, acc = 0.f;

  const int4* xp = (const int4*)(x + (size_t)b * 512);  // [T][8] ids, 2 int4 per step
  int4 ia = xp[0], ib = xp[1];
  const float4* tf4 = (const float4*)sTf;

  #pragma unroll 1
  for (int t = 0; t < 64; ++t) {
    // prefetch next step's ids (hides L1/HBM latency under this step's compute)
    const int tn = (t < 63) ? (2*t + 2) : 126;
    int4 na = xp[tn], nb = xp[tn+1];
    const float w3t = sW3[t];

    // ---- layer 0 input gates: gather fused-table rows (bias pre-folded) ----
    float4 g0 = tf4[(      ia.x)*8 + j];
    float4 g1 = tf4[(  2 + ia.y)*8 + j];
    float4 g2 = tf4[(  4 + ia.z)*8 + j];
    float4 g3 = tf4[( 25 + ia.w)*8 + j];
    float4 g4 = tf4[( 47 + ib.x)*8 + j];
    float4 g5 = tf4[( 52 + ib.y)*8 + j];
    float4 g6 = tf4[( 54 + ib.z)*8 + j];
    float4 g7 = tf4[( 76 + ib.w)*8 + j];
    float gi = ((g0.x+g1.x)+(g2.x+g3.x)) + ((g4.x+g5.x)+(g6.x+g7.x));
    float gf = ((g0.y+g1.y)+(g2.y+g3.y)) + ((g4.y+g5.y)+(g6.y+g7.y));
    float gg = ((g0.z+g1.z)+(g2.z+g3.z)) + ((g4.z+g5.z)+(g6.z+g7.z));
    float go = ((g0.w+g1.w)+(g2.w+g3.w)) + ((g4.w+g5.w)+(g6.w+g7.w));

    // ---- layer 0 recurrence ----
    #pragma unroll
    for (int k = 0; k < 8; ++k) {
      gi = fmaf(wr0[k],    h0v[k], gi);
      gf = fmaf(wr0[8+k],  h0v[k], gf);
      gg = fmaf(wr0[16+k], h0v[k], gg);
      go = fmaf(wr0[24+k], h0v[k], go);
    }
    float si = sigf(gi), sf = sigf(gf), tg = tanh_fast(gg), so = sigf(go);
    c0 = fmaf(sf, c0, si * tg);
    float h0 = so * tanh_fast(c0);

    sH0[tid] = h0;  // in-wave broadcast (8-lane groups never cross a wave)

    // independent work between LDS write and read: W_hh1 * h1_prev
    float Gi = b1v.x, Gf = b1v.y, Gg = b1v.z, Go = b1v.w;
    #pragma unroll
    for (int k = 0; k < 8; ++k) {
      Gi = fmaf(wr1[k],    h1v[k], Gi);
      Gf = fmaf(wr1[8+k],  h1v[k], Gf);
      Gg = fmaf(wr1[16+k], h1v[k], Gg);
      Go = fmaf(wr1[24+k], h1v[k], Go);
    }
    {
      const float4* ph = (const float4*)&sH0[tid & ~7];
      float4 lo = ph[0], hi = ph[1];
      h0v[0]=lo.x; h0v[1]=lo.y; h0v[2]=lo.z; h0v[3]=lo.w;
      h0v[4]=hi.x; h0v[5]=hi.y; h0v[6]=hi.z; h0v[7]=hi.w;
    }
    #pragma unroll
    for (int k = 0; k < 8; ++k) {
      Gi = fmaf(wi1[k],    h0v[k], Gi);
      Gf = fmaf(wi1[8+k],  h0v[k], Gf);
      Gg = fmaf(wi1[16+k], h0v[k], Gg);
      Go = fmaf(wi1[24+k], h0v[k], Go);
    }
    float si1 = sigf(Gi), sf1 = sigf(Gf), tg1 = tanh_fast(Gg), so1 = sigf(Go);
    c1 = fmaf(sf1, c1, si1 * tg1);
    float h1 = so1 * tanh_fast(c1);

    sH1[tid] = h1;
    {
      const float4* ph = (const float4*)&sH1[tid & ~7];
      float4 lo = ph[0], hi = ph[1];
      h1v[0]=lo.x; h1v[1]=lo.y; h1v[2]=lo.z; h1v[3]=lo.w;
      h1v[4]=hi.x; h1v[5]=hi.y; h1v[6]=hi.z; h1v[7]=hi.w;
    }

    // ---- collapsed FC heads + time accumulation (redundant across 8 lanes) ----
    float th = cth, hf = chh;
    #pragma unroll
    for (int k = 0; k < 8; ++k) {
      th = fmaf(uu[k], h1v[k], th);
      hf = fmaf(vv[k], h1v[k], hf);
    }
    acc = fmaf(th * hf, w3t, acc);

    ia = na; ib = nb;
  }

  if (j == 0) out[b] = acc + fc3b;
}

extern "C" void kernel_launch(void* const* d_in, const int* in_sizes, int n_in,
                              void* d_out, int out_size, void* d_ws, size_t ws_size,
                              hipStream_t stream) {
  const int* x = (const int*)d_in[0];
  const float *E1=(const float*)d_in[1],  *E2=(const float*)d_in[2],
              *E3=(const float*)d_in[3],  *E4=(const float*)d_in[4],
              *E5=(const float*)d_in[5],  *E6=(const float*)d_in[6],
              *E7=(const float*)d_in[7],  *E8=(const float*)d_in[8];
  const float *Wih0=(const float*)d_in[9],  *Whh0=(const float*)d_in[10],
              *bih0=(const float*)d_in[11], *bhh0=(const float*)d_in[12],
              *Wih1=(const float*)d_in[13], *Whh1=(const float*)d_in[14],
              *bih1=(const float*)d_in[15], *bhh1=(const float*)d_in[16],
              *fc6w=(const float*)d_in[17], *fc6b=(const float*)d_in[18],
              *fc7w=(const float*)d_in[19], *fc7b=(const float*)d_in[20],
              *fc1w=(const float*)d_in[21], *fc1b=(const float*)d_in[22],
              *fc2w=(const float*)d_in[23], *fc2b=(const float*)d_in[24],
              *fc3w=(const float*)d_in[25], *fc3b=(const float*)d_in[26];

  lstm_fused<<<512, 256, 0, stream>>>(
      x, E1,E2,E3,E4,E5,E6,E7,E8,
      Wih0, Whh0, bih0, bhh0, Wih1, Whh1, bih1, bhh1,
      fc6w, fc6b, fc7w, fc7b, fc1w, fc1b, fc2w, fc2b, fc3w, fc3b,
      (float*)d_out);
}

// Round 5
// 167.849 us; speedup vs baseline: 1.0437x; 1.0437x over previous
//
#include <hip/hip_runtime.h>
#include <hip/hip_bf16.h>

typedef float f2 __attribute__((ext_vector_type(2)));

// fast sigmoid / tanh via native v_exp_f32 + v_rcp_f32 (~1e-6 rel err vs threshold 7.8e-4)
__device__ __forceinline__ float sigf(float x) {
  return __builtin_amdgcn_rcpf(1.0f + __expf(-x));
}
__device__ __forceinline__ float tanh_fast(float x) {
  return fmaf(-2.0f, __builtin_amdgcn_rcpf(1.0f + __expf(2.0f * x)), 1.0f);
}

// B=16384, T=64, H=8. 8 lanes per batch element (lane j = hidden unit j).
// Block = 256 threads = 32 elements; grid = 512 blocks = 2 blocks/CU (8 waves/CU).
__launch_bounds__(256, 2)
__global__ void lstm_fused(
    const int* __restrict__ x,
    const float* __restrict__ e1, const float* __restrict__ e2,
    const float* __restrict__ e3, const float* __restrict__ e4,
    const float* __restrict__ e5, const float* __restrict__ e6,
    const float* __restrict__ e7, const float* __restrict__ e8,
    const float* __restrict__ W_ih0, const float* __restrict__ W_hh0,
    const float* __restrict__ b_ih0, const float* __restrict__ b_hh0,
    const float* __restrict__ W_ih1, const float* __restrict__ W_hh1,
    const float* __restrict__ b_ih1, const float* __restrict__ b_hh1,
    const float* __restrict__ fc6_w, const float* __restrict__ fc6_b,
    const float* __restrict__ fc7_w, const float* __restrict__ fc7_b,
    const float* __restrict__ fc1_w, const float* __restrict__ fc1_b,
    const float* __restrict__ fc2_w, const float* __restrict__ fc2_b,
    const float* __restrict__ fc3_w, const float* __restrict__ fc3_b,
    float* __restrict__ out)
{
  // Fused embedding×W_ih0 tables: 100 rows × 32 gate-values, per-unit permuted:
  // sTf[row*32 + j*4 + q]  (q: 0=i,1=f,2=g,3=o for unit j) -> float4 per (row,j)
  __shared__ __align__(16) float sTf[3200];
  __shared__ float sW3[64];
  __shared__ __align__(16) float sH0[256];
  __shared__ __align__(16) float sH1[256];

  const int tid = threadIdx.x;

  // ---- build fused input tables in LDS ----
  {
    constexpr int RO[8]  = {0,2,4,25,47,52,54,76};
    constexpr int ED[8]  = {1,1,3,3,1,1,3,3};
    constexpr int CO[8]  = {0,1,2,5,8,9,10,13};
    constexpr int VOC[8] = {2,2,21,22,5,2,22,24};
    const float* ep[8] = {e1,e2,e3,e4,e5,e6,e7,e8};
    #pragma unroll
    for (int f = 0; f < 8; ++f) {
      const float* E = ep[f];
      for (int idx = tid; idx < VOC[f]*32; idx += 256) {
        int v = idx >> 5, m = idx & 31;
        int jj = m >> 2, q = m & 3, g = q*8 + jj;
        float s = 0.0f;
        #pragma unroll
        for (int d = 0; d < ED[f]; ++d)
          s += E[v*ED[f]+d] * W_ih0[g*16 + CO[f] + d];
        if (f == 0) s += b_ih0[g] + b_hh0[g];  // fold both biases into feat-0 table
        sTf[(RO[f]+v)*32 + m] = s;
      }
    }
    if (tid < 64) sW3[tid] = fc3_w[tid];
  }
  __syncthreads();

  const int j = tid & 7;                         // hidden unit owned by this lane
  const int b = (blockIdx.x << 5) + (tid >> 3);  // batch element

  // ---- per-lane recurrent weights packed as float2 (gate-pairs (i,f) and (g,o)) ----
  f2 wIF0[8], wGO0[8], iIF1[8], iGO1[8], rIF1[8], rGO1[8];
  {
    const float4* P;
    float4 I0,I1,F0,F1,G0,G1,O0,O1;
    #define LOADROWS(M) \
      P = (const float4*)(M); \
      I0 = P[(0*8+j)*2]; I1 = P[(0*8+j)*2+1]; \
      F0 = P[(1*8+j)*2]; F1 = P[(1*8+j)*2+1]; \
      G0 = P[(2*8+j)*2]; G1 = P[(2*8+j)*2+1]; \
      O0 = P[(3*8+j)*2]; O1 = P[(3*8+j)*2+1];
    #define PACK(dIF, dGO) \
      dIF[0]=(f2){I0.x,F0.x}; dIF[1]=(f2){I0.y,F0.y}; dIF[2]=(f2){I0.z,F0.z}; dIF[3]=(f2){I0.w,F0.w}; \
      dIF[4]=(f2){I1.x,F1.x}; dIF[5]=(f2){I1.y,F1.y}; dIF[6]=(f2){I1.z,F1.z}; dIF[7]=(f2){I1.w,F1.w}; \
      dGO[0]=(f2){G0.x,O0.x}; dGO[1]=(f2){G0.y,O0.y}; dGO[2]=(f2){G0.z,O0.z}; dGO[3]=(f2){G0.w,O0.w}; \
      dGO[4]=(f2){G1.x,O1.x}; dGO[5]=(f2){G1.y,O1.y}; dGO[6]=(f2){G1.z,O1.z}; dGO[7]=(f2){G1.w,O1.w};
    LOADROWS(W_hh0); PACK(wIF0, wGO0);
    LOADROWS(W_ih1); PACK(iIF1, iGO1);
    LOADROWS(W_hh1); PACK(rIF1, rGO1);
    #undef LOADROWS
    #undef PACK
  }
  const f2 bIF1 = {b_ih1[j]    + b_hh1[j],    b_ih1[8+j]  + b_hh1[8+j]};
  const f2 bGO1 = {b_ih1[16+j] + b_hh1[16+j], b_ih1[24+j] + b_hh1[24+j]};

  // ---- collapsed FC heads packed: thf = (theta, h) = sum_k uvk[k]*h1[k] + cc ----
  f2 uvk[8];
  float f7[4], f2c[4];
  #pragma unroll
  for (int q = 0; q < 4; ++q) { f7[q] = fc7_w[q]; f2c[q] = fc2_w[q]; }
  #pragma unroll
  for (int k = 0; k < 8; ++k) {
    float s1 = 0.f, s2 = 0.f;
    #pragma unroll
    for (int q = 0; q < 4; ++q) {
      s1 += f7[q]  * fc6_w[q*8+k];
      s2 += f2c[q] * fc1_w[q*8+k];
    }
    uvk[k] = (f2){s1, s2};
  }
  float cth = fc7_b[0], chh = fc2_b[0];
  #pragma unroll
  for (int q = 0; q < 4; ++q) { cth += f7[q]*fc6_b[q]; chh += f2c[q]*fc1_b[q]; }
  const f2 cc = {cth, chh};
  const float fc3b = fc3_b[0];

  // ---- state ----
  float h0s[8];
  #pragma unroll
  for (int k = 0; k < 8; ++k) h0s[k] = 0.f;
  float c0 = 0.f, c1 = 0.f, acc = 0.f;

  sH1[tid] = 0.f;  // pre-init: read at top of t=0 before first write (in-wave ordering)

  const int4* xp = (const int4*)(x + (size_t)b * 512);
  int4 ia = xp[0], ib = xp[1];
  const float4* tf4 = (const float4*)sTf;
  const float4* ph0 = (const float4*)&sH0[tid & ~7];
  const float4* ph1 = (const float4*)&sH1[tid & ~7];

  #pragma unroll 1
  for (int t = 0; t < 64; ++t) {
    // (1) issue read of h1(t-1) early — latency hides under gather + layer-0 work
    float4 h1A = ph1[0], h1B = ph1[1];
    float h1s[8] = {h1A.x,h1A.y,h1A.z,h1A.w,h1B.x,h1B.y,h1B.z,h1B.w};

    // (2) prefetch next step's ids
    const int tn = (t < 63) ? (2*t + 2) : 126;
    int4 na = xp[tn], nb = xp[tn+1];
    const float w3p = (t == 0) ? 0.f : sW3[t-1];   // FC of step t-1 folded into step t

    // (3) layer-0 input gates: gather fused-table rows (bias pre-folded)
    float4 g0 = tf4[(      ia.x)*8 + j];
    float4 g1 = tf4[(  2 + ia.y)*8 + j];
    float4 g2 = tf4[(  4 + ia.z)*8 + j];
    float4 g3 = tf4[( 25 + ia.w)*8 + j];
    float4 g4 = tf4[( 47 + ib.x)*8 + j];
    float4 g5 = tf4[( 52 + ib.y)*8 + j];
    float4 g6 = tf4[( 54 + ib.z)*8 + j];
    float4 g7 = tf4[( 76 + ib.w)*8 + j];
    f2 gIF = (((f2){g0.x,g0.y} + (f2){g1.x,g1.y}) + ((f2){g2.x,g2.y} + (f2){g3.x,g3.y}))
           + (((f2){g4.x,g4.y} + (f2){g5.x,g5.y}) + ((f2){g6.x,g6.y} + (f2){g7.x,g7.y}));
    f2 gGO = (((f2){g0.z,g0.w} + (f2){g1.z,g1.w}) + ((f2){g2.z,g2.w} + (f2){g3.z,g3.w}))
           + (((f2){g4.z,g4.w} + (f2){g5.z,g5.w}) + ((f2){g6.z,g6.w} + (f2){g7.z,g7.w}));

    // (4) layer-0 recurrence (packed), activations, write h0
    #pragma unroll
    for (int k = 0; k < 8; ++k) {
      f2 hb = (f2)(h0s[k]);
      gIF = __builtin_elementwise_fma(wIF0[k], hb, gIF);
      gGO = __builtin_elementwise_fma(wGO0[k], hb, gGO);
    }
    float si = sigf(gIF.x), sf = sigf(gIF.y), tg = tanh_fast(gGO.x), so = sigf(gGO.y);
    c0 = fmaf(sf, c0, si * tg);
    float h0 = so * tanh_fast(c0);
    sH0[tid] = h0;  // in-wave broadcast

    // (5) work independent of the h0 read: W_hh1*h1(t-1) and deferred FC(t-1)
    f2 GIF = bIF1, GGO = bGO1, thf = cc;
    #pragma unroll
    for (int k = 0; k < 8; ++k) {
      f2 hb = (f2)(h1s[k]);
      GIF = __builtin_elementwise_fma(rIF1[k], hb, GIF);
      GGO = __builtin_elementwise_fma(rGO1[k], hb, GGO);
      thf = __builtin_elementwise_fma(uvk[k],  hb, thf);
    }
    acc = fmaf(thf.x * thf.y, w3p, acc);

    // (6) read h0 back (exchange across the 8-lane group)
    {
      float4 lo = ph0[0], hi = ph0[1];
      h0s[0]=lo.x; h0s[1]=lo.y; h0s[2]=lo.z; h0s[3]=lo.w;
      h0s[4]=hi.x; h0s[5]=hi.y; h0s[6]=hi.z; h0s[7]=hi.w;
    }

    // (7) layer-1 input matvec, activations, write h1 (read deferred to t+1)
    #pragma unroll
    for (int k = 0; k < 8; ++k) {
      f2 hb = (f2)(h0s[k]);
      GIF = __builtin_elementwise_fma(iIF1[k], hb, GIF);
      GGO = __builtin_elementwise_fma(iGO1[k], hb, GGO);
    }
    float si1 = sigf(GIF.x), sf1 = sigf(GIF.y), tg1 = tanh_fast(GGO.x), so1 = sigf(GGO.y);
    c1 = fmaf(sf1, c1, si1 * tg1);
    float h1 = so1 * tanh_fast(c1);
    sH1[tid] = h1;

    ia = na; ib = nb;
  }

  // epilogue: FC for t=63
  {
    float4 h1A = ph1[0], h1B = ph1[1];
    float h1s[8] = {h1A.x,h1A.y,h1A.z,h1A.w,h1B.x,h1B.y,h1B.z,h1B.w};
    f2 thf = cc;
    #pragma unroll
    for (int k = 0; k < 8; ++k)
      thf = __builtin_elementwise_fma(uvk[k], (f2)(h1s[k]), thf);
    acc = fmaf(thf.x * thf.y, sW3[63], acc);
  }

  if (j == 0) out[b] = acc + fc3b;
}

extern "C" void kernel_launch(void* const* d_in, const int* in_sizes, int n_in,
                              void* d_out, int out_size, void* d_ws, size_t ws_size,
                              hipStream_t stream) {
  const int* x = (const int*)d_in[0];
  const float *E1=(const float*)d_in[1],  *E2=(const float*)d_in[2],
              *E3=(const float*)d_in[3],  *E4=(const float*)d_in[4],
              *E5=(const float*)d_in[5],  *E6=(const float*)d_in[6],
              *E7=(const float*)d_in[7],  *E8=(const float*)d_in[8];
  const float *Wih0=(const float*)d_in[9],  *Whh0=(const float*)d_in[10],
              *bih0=(const float*)d_in[11], *bhh0=(const float*)d_in[12],
              *Wih1=(const float*)d_in[13], *Whh1=(const float*)d_in[14],
              *bih1=(const float*)d_in[15], *bhh1=(const float*)d_in[16],
              *fc6w=(const float*)d_in[17], *fc6b=(const float*)d_in[18],
              *fc7w=(const float*)d_in[19], *fc7b=(const float*)d_in[20],
              *fc1w=(const float*)d_in[21], *fc1b=(const float*)d_in[22],
              *fc2w=(const float*)d_in[23], *fc2b=(const float*)d_in[24],
              *fc3w=(const float*)d_in[25], *fc3b=(const float*)d_in[26];

  lstm_fused<<<512, 256, 0, stream>>>(
      x, E1,E2,E3,E4,E5,E6,E7,E8,
      Wih0, Whh0, bih0, bhh0, Wih1, Whh1, bih1, bhh1,
      fc6w, fc6b, fc7w, fc7b, fc1w, fc1b, fc2w, fc2b, fc3w, fc3b,
      (float*)d_out);
}